// Round 9
// baseline (149.601 us; speedup 1.0000x reference)
//
#include <hip/hip_runtime.h>

// Round 9: BARRIER-FREE flash attention. Each warp owns a private K+V LDS slab
// (single-buffered, phase-split DMA: K staged after QK, V after PV), counted
// per-wave vmcnt(8)/(9) — no __syncthreads in the main loop, waves drift freely.
// Structure otherwise = round 8 (q_w=32/warp, 2 qw x 4 g, conflict-free layouts).
//   d_in: 0=x f32, 1=mask i32, 2=Wk, 3=Wq, 4=Wv
// ws (f16): qT [BT/32][8192] | kT [BT/16][4096] | vT [BT/16][4096]
//   qT: [(qh*8+kc)*512 + l4*128 + tok*8 + j]  (x1/16 folded)
//   kT: [kc*512 + ch*128 + key*8 + j]   <-> K[16t+key][kc*32+ch*8+j]
//   vT: [dt*512 + kh*256 + d31*8 + j]   <-> V^T[dt*32+d31][16t+kh*8+j]

typedef __attribute__((ext_vector_type(8)))  _Float16 f16x8;
typedef __attribute__((ext_vector_type(4)))  _Float16 f16x4;
typedef __attribute__((ext_vector_type(4)))  float    f32x4;
typedef __attribute__((ext_vector_type(16))) float    f32x16;

constexpr int Bb = 4;
constexpr int Tt = 4096;
constexpr int Cc = 256;
constexpr int BT = Bb * Tt;
constexpr int NI = 64;                 // per-warp: 64 tiles x 16 keys = 1024 keys (T/4)

#define MFMA16(a, b, c) __builtin_amdgcn_mfma_f32_16x16x32_f16((a), (b), (c), 0, 0, 0)
#define MFMA32(a, b, c) __builtin_amdgcn_mfma_f32_32x32x16_f16((a), (b), (c), 0, 0, 0)

__device__ __forceinline__ void gl16(const _Float16* gp, char* lp) {
    __builtin_amdgcn_global_load_lds(
        (const __attribute__((address_space(1))) void*)gp,
        (__attribute__((address_space(3))) void*)lp, 16, 0, 0);
}

// ---------------- Kernel A: fused QKV projection (verbatim round 8) ----------
__global__ __launch_bounds__(256) void qkv_proj(
    const float* __restrict__ x,
    const float* __restrict__ Wq, const float* __restrict__ Wk,
    const float* __restrict__ Wv,
    _Float16* __restrict__ qo, _Float16* __restrict__ ko,
    _Float16* __restrict__ vto)
{
    extern __shared__ _Float16 sm[];
    _Float16* xs = sm;              // [128][264]
    _Float16* wsm = sm + 128 * 264; // [128][264]

    const int tid = threadIdx.x;
    const int m0  = blockIdx.x * 128;
    const int ny  = blockIdx.y;
    const int mat = ny >> 1;              // 0=q 1=k 2=v
    const int d0  = (ny & 1) * 128;
    const float* W = (mat == 0) ? Wq : (mat == 1 ? Wk : Wv);

#pragma unroll
    for (int i = 0; i < 32; ++i) {
        int flat = i * 256 + tid;
        int r = flat >> 6, c4 = (flat & 63) << 2;
        float4 v = *reinterpret_cast<const float4*>(x + (size_t)(m0 + r) * Cc + c4);
        f16x4 h = { (_Float16)v.x, (_Float16)v.y, (_Float16)v.z, (_Float16)v.w };
        *reinterpret_cast<f16x4*>(xs + r * 264 + c4) = h;
    }
#pragma unroll
    for (int i = 0; i < 32; ++i) {
        int flat = i * 256 + tid;
        int r = flat >> 6, c4 = (flat & 63) << 2;
        float4 v = *reinterpret_cast<const float4*>(W + (size_t)(d0 + r) * Cc + c4);
        f16x4 h = { (_Float16)v.x, (_Float16)v.y, (_Float16)v.z, (_Float16)v.w };
        *reinterpret_cast<f16x4*>(wsm + r * 264 + c4) = h;
    }
    __syncthreads();

    const int w = tid >> 6, lane = tid & 63;
    const int lr = lane & 15, lg = lane >> 4;

    f32x4 acc[2][8] = {};

#pragma unroll
    for (int kc = 0; kc < 8; ++kc) {
        const int c0 = kc * 32 + lg * 8;
        f16x8 xf[2], wf[8];
#pragma unroll
        for (int mb = 0; mb < 2; ++mb)
            xf[mb] = *reinterpret_cast<const f16x8*>(xs + (w * 32 + mb * 16 + lr) * 264 + c0);
#pragma unroll
        for (int db = 0; db < 8; ++db)
            wf[db] = *reinterpret_cast<const f16x8*>(wsm + (db * 16 + lr) * 264 + c0);
        if (mat != 2) {
#pragma unroll
            for (int mb = 0; mb < 2; ++mb)
#pragma unroll
                for (int db = 0; db < 8; ++db)
                    acc[mb][db] = MFMA16(wf[db], xf[mb], acc[mb][db]);   // D[d][tok]
        } else {
#pragma unroll
            for (int mb = 0; mb < 2; ++mb)
#pragma unroll
                for (int db = 0; db < 8; ++db)
                    acc[mb][db] = MFMA16(xf[mb], wf[db], acc[mb][db]);   // D[tok][d]
        }
    }

    if (mat != 2) {
        const float sc = (mat == 0) ? 0.0625f : 1.0f;
        const int jj  = (lg & 1) * 4;
#pragma unroll
        for (int mb = 0; mb < 2; ++mb)
#pragma unroll
            for (int db = 0; db < 8; ++db) {
                int m  = m0 + w * 32 + mb * 16 + lr;
                int c  = d0 + db * 16 + lg * 4;
                int kc = c >> 5;
                int ch = (c >> 3) & 3;
                f32x4 a = acc[mb][db];
                f16x4 h = { (_Float16)(a.x * sc), (_Float16)(a.y * sc),
                            (_Float16)(a.z * sc), (_Float16)(a.w * sc) };
                if (mat == 0) {
                    size_t off = (size_t)(m >> 5) * 8192 + (((m >> 4) & 1) * 8 + kc) * 512
                               + ch * 128 + (m & 15) * 8 + jj;
                    *reinterpret_cast<f16x4*>(qo + off) = h;
                } else {
                    size_t off = (size_t)(m >> 4) * 4096 + kc * 512
                               + ch * 128 + (m & 15) * 8 + jj;
                    *reinterpret_cast<f16x4*>(ko + off) = h;
                }
            }
    } else {
        const int jj = (lg & 1) * 4;
        const int kh = (lg >> 1) & 1;
#pragma unroll
        for (int mb = 0; mb < 2; ++mb)
#pragma unroll
            for (int db = 0; db < 8; ++db) {
                int d = d0 + db * 16 + lr;
                int m = m0 + w * 32 + mb * 16 + lg * 4;
                f32x4 a = acc[mb][db];
                f16x4 h = { (_Float16)a.x, (_Float16)a.y, (_Float16)a.z, (_Float16)a.w };
                size_t off = (size_t)(m >> 4) * 4096 + (d >> 5) * 512
                           + kh * 256 + (d & 31) * 8 + jj;
                *reinterpret_cast<f16x4*>(vto + off) = h;
            }
    }
}

// ---------------- Kernel B: barrier-free flash attention ----------------
// LDS map (bytes): [0,131072)   8 x private warp slab [K 8KB | V 8KB]
//                  [131072,143360) per-warp P [8][32][24] f16
//                  [143360,144384) mex f32[2][4][32]; [144384,145408) lex
// epilogue reuses [0,132096) as oex f32[4][32][258]
__global__ __launch_bounds__(512, 2) void attn_kernel(
    const _Float16* __restrict__ qb, const _Float16* __restrict__ kb,
    const _Float16* __restrict__ vtb, const int* __restrict__ mask,
    float* __restrict__ outp)
{
    extern __shared__ char smraw[];
    float* mex32 = (float*)(smraw + 143360);
    float* lex32 = (float*)(smraw + 144384);
    float* oexf  = (float*)smraw;

    const int tid = threadIdx.x, w = tid >> 6, lane = tid & 63;
    const int qw = w >> 2, g = w & 3;
    const int l15 = lane & 15, l4 = lane >> 4;
    const int l31 = lane & 31, l5 = lane >> 5;

    const int bid = blockIdx.x;
    const int b   = (bid & 7) >> 1;                    // batch -> XCD pair
    const int qt  = ((bid >> 3) << 1) | (bid & 1);     // [0,64)
    const int q0  = qt * 64;
    const size_t base = (size_t)b * Tt * Cc;
    const int* maskb = mask + (size_t)b * Tt;
    const _Float16* kTb = kb + base;
    const _Float16* vTb = vtb + base;

    // Q fragments: Q[q0 + qw*32 + qh*16 + l15][kc*32 + l4*8 + j]
    f16x8 qf[2][8];
    {
        const _Float16* qTb = qb + (size_t)(b * 128 + qt * 2 + qw) * 8192;
#pragma unroll
        for (int qh = 0; qh < 2; ++qh)
#pragma unroll
            for (int kc = 0; kc < 8; ++kc)
                qf[qh][kc] = *reinterpret_cast<const f16x8*>(
                    qTb + (qh * 8 + kc) * 512 + l4 * 128 + l15 * 8);
    }

    char* kbase = smraw + w * 16384;            // private K tile (8 KB)
    char* vbase = kbase + 8192;                 // private V tile (8 KB)
    const _Float16* kbL = (const _Float16*)kbase;
    const _Float16* vbL = (const _Float16*)vbase;
    _Float16* pw = (_Float16*)(smraw + 131072) + w * 768;   // [32][24]

    f32x16 o[8] = {};                  // O^T[d = dt*32+(r&3)+8*(r>>2)+4*l5][q=l31]
    float m_run = -60.f, l0r = 0.f, l1r = 0.f;

    // this warp's key quarter: tiles [g*64, g*64+64)
    auto STAGE_K = [&](int i) {
        const _Float16* src = kTb + (size_t)(g * 64 + i) * 4096 + lane * 8;
#pragma unroll
        for (int j = 0; j < 8; ++j) gl16(src + j * 512, kbase + j * 1024);
    };
    auto STAGE_V = [&](int i) {
        const _Float16* src = vTb + (size_t)(g * 64 + i) * 4096 + lane * 8;
#pragma unroll
        for (int j = 0; j < 8; ++j) gl16(src + j * 512, vbase + j * 1024);
    };

    // prologue: mask0(1), K0(8), V0(8) in flight = 17
    int4 mcur = *reinterpret_cast<const int4*>(maskb + (g * 64) * 16 + l4 * 4);
    STAGE_K(0);
    STAGE_V(0);

#pragma unroll 1
    for (int i = 0; i < NI; ++i) {
        // drain mask_i + K_i (leaves V_i's 8 in flight)
        asm volatile("s_waitcnt vmcnt(8)" ::: "memory");

        // ---- QK: S^T[key = l4*4 + r][q = qh*16 + l15] ----
        f32x4 s40 = { 0.f, 0.f, 0.f, 0.f }, s41 = { 0.f, 0.f, 0.f, 0.f };
        __builtin_amdgcn_s_setprio(1);
#pragma unroll
        for (int kc = 0; kc < 8; ++kc) {
            f16x8 kf = *reinterpret_cast<const f16x8*>(kbL + kc * 512 + l4 * 128 + l15 * 8);
            s40 = MFMA16(kf, qf[0][kc], s40);
            s41 = MFMA16(kf, qf[1][kc], s41);
        }
        __builtin_amdgcn_s_setprio(0);

        // K reads drained -> safe to overwrite K tile; issue mask_{i+1} + K_{i+1}
        asm volatile("s_waitcnt lgkmcnt(0)" ::: "memory");
        int4 mnext = mcur;
        if (i + 1 < NI) {
            mnext = *reinterpret_cast<const int4*>(
                maskb + (g * 64 + i + 1) * 16 + l4 * 4);
            STAGE_K(i + 1);
        }

        if (mcur.x == 0) { s40[0] = -1e30f; s41[0] = -1e30f; }
        if (mcur.y == 0) { s40[1] = -1e30f; s41[1] = -1e30f; }
        if (mcur.z == 0) { s40[2] = -1e30f; s41[2] = -1e30f; }
        if (mcur.w == 0) { s40[3] = -1e30f; s41[3] = -1e30f; }

        // online softmax, single merged max for both qh (q = l15 / 16+l15)
        float t0 = fmaxf(fmaxf(s40[0], s40[1]), fmaxf(s40[2], s40[3]));
        float t1 = fmaxf(fmaxf(s41[0], s41[1]), fmaxf(s41[2], s41[3]));
        float tm = fmaxf(t0, t1);
        tm = fmaxf(tm, __shfl_xor(tm, 16, 64));
        tm = fmaxf(tm, __shfl_xor(tm, 32, 64));

        if (__any(tm > m_run + 8.f)) {            // defer-max
            float mn = fmaxf(m_run, tm);
            float cs = __expf(m_run - mn);
            m_run = mn; l0r *= cs; l1r *= cs;
#pragma unroll
            for (int dt = 0; dt < 8; ++dt) o[dt] *= cs;
        }

        float rs0 = 0.f, rs1 = 0.f;
#pragma unroll
        for (int r = 0; r < 4; ++r) {
            float p0 = __expf(s40[r] - m_run); s40[r] = p0; rs0 += p0;
            float p1 = __expf(s41[r] - m_run); s41[r] = p1; rs1 += p1;
        }
        rs0 += __shfl_xor(rs0, 16, 64); rs0 += __shfl_xor(rs0, 32, 64);
        rs1 += __shfl_xor(rs1, 16, 64); rs1 += __shfl_xor(rs1, 32, 64);
        l0r += rs0; l1r += rs1;

        // P -> pw[q][k] f16; reread as PV B-frag (in-wave RAW, lgkm-ordered)
        {
            f16x4 h0 = { (_Float16)s40[0], (_Float16)s40[1], (_Float16)s40[2], (_Float16)s40[3] };
            f16x4 h1 = { (_Float16)s41[0], (_Float16)s41[1], (_Float16)s41[2], (_Float16)s41[3] };
            *reinterpret_cast<f16x4*>(pw + l15 * 24 + l4 * 4)        = h0;
            *reinterpret_cast<f16x4*>(pw + (16 + l15) * 24 + l4 * 4) = h1;
        }
        f16x8 pf = *reinterpret_cast<const f16x8*>(pw + l31 * 24 + l5 * 8);

        // drain V_i (counted: mask_{i+1}+K_{i+1} = 9 still in flight)
        if (i + 1 < NI) asm volatile("s_waitcnt vmcnt(9)" ::: "memory");
        else            asm volatile("s_waitcnt vmcnt(0)" ::: "memory");

        // ---- PV: O^T += V^T P^T (32x32x16) ----
        __builtin_amdgcn_s_setprio(1);
#pragma unroll
        for (int dt = 0; dt < 8; ++dt) {
            f16x8 vf = *reinterpret_cast<const f16x8*>(vbL + dt * 512 + l5 * 256 + l31 * 8);
            o[dt] = MFMA32(vf, pf, o[dt]);
        }
        __builtin_amdgcn_s_setprio(0);

        // V reads drained -> overwrite V tile with V_{i+1}
        asm volatile("s_waitcnt lgkmcnt(0)" ::: "memory");
        if (i + 1 < NI) STAGE_V(i + 1);
        mcur = mnext;
    }
    __syncthreads();   // first barrier since launch: all warps done; reuse LDS

    // ---- epilogue: 4-group split-K merge, two qw passes (round 8) ----
    if (l4 == 0) {
        mex32[(qw * 4 + g) * 32 + l15]      = m_run;
        mex32[(qw * 4 + g) * 32 + 16 + l15] = m_run;
        lex32[(qw * 4 + g) * 32 + l15]      = l0r;
        lex32[(qw * 4 + g) * 32 + 16 + l15] = l1r;
    }
    __syncthreads();

    float mst = -1e30f;
#pragma unroll
    for (int g2 = 0; g2 < 4; ++g2)
        mst = fmaxf(mst, mex32[(qw * 4 + g2) * 32 + l31]);
    float osc = __expf(m_run - mst);

#pragma unroll 1
    for (int s = 0; s < 2; ++s) {
        if (qw == s) {
            float* og = oexf + g * (32 * 258);
#pragma unroll
            for (int dt = 0; dt < 8; ++dt)
#pragma unroll
                for (int r = 0; r < 16; ++r) {
                    int d = dt * 32 + (r & 3) + 8 * (r >> 2) + 4 * l5;
                    og[l31 * 258 + d] = o[dt][r] * osc;
                }
        }
        __syncthreads();
        {
            const int q = tid >> 4, dg = tid & 15;
            float mA = mex32[(s * 4 + 0) * 32 + q], mB = mex32[(s * 4 + 1) * 32 + q];
            float mC = mex32[(s * 4 + 2) * 32 + q], mD = mex32[(s * 4 + 3) * 32 + q];
            float ms = fmaxf(fmaxf(mA, mB), fmaxf(mC, mD));
            float lt = lex32[(s * 4 + 0) * 32 + q] * __expf(mA - ms)
                     + lex32[(s * 4 + 1) * 32 + q] * __expf(mB - ms)
                     + lex32[(s * 4 + 2) * 32 + q] * __expf(mC - ms)
                     + lex32[(s * 4 + 3) * 32 + q] * __expf(mD - ms);
            float inv = 1.f / lt;
#pragma unroll
            for (int i = 0; i < 4; ++i) {
                int d0 = dg * 16 + i * 4;
                f32x4 a = *reinterpret_cast<const f32x4*>(oexf + q * 258 + d0);
#pragma unroll
                for (int g2 = 1; g2 < 4; ++g2) {
                    f32x4 t = *reinterpret_cast<const f32x4*>(
                        oexf + g2 * (32 * 258) + q * 258 + d0);
                    a[0] += t[0]; a[1] += t[1]; a[2] += t[2]; a[3] += t[3];
                }
                a[0] *= inv; a[1] *= inv; a[2] *= inv; a[3] *= inv;
                *reinterpret_cast<f32x4*>(
                    outp + base + (size_t)(q0 + s * 32 + q) * Cc + d0) = a;
            }
        }
        __syncthreads();
    }
}

extern "C" void kernel_launch(void* const* d_in, const int* in_sizes, int n_in,
                              void* d_out, int out_size, void* d_ws, size_t ws_size,
                              hipStream_t stream)
{
    (void)in_sizes; (void)n_in; (void)out_size; (void)ws_size;
    const float* x   = (const float*)d_in[0];
    const int*  mask = (const int*)d_in[1];
    const float* Wk  = (const float*)d_in[2];
    const float* Wq  = (const float*)d_in[3];
    const float* Wv  = (const float*)d_in[4];
    float* out = (float*)d_out;

    _Float16* q  = (_Float16*)d_ws;
    _Float16* k  = q + (size_t)BT * Cc;
    _Float16* vt = k + (size_t)BT * Cc;

    dim3 gA(128, 6), blkA(256);
    size_t ldsA = (size_t)(128 + 128) * 264 * sizeof(_Float16);
    qkv_proj<<<gA, blkA, ldsA, stream>>>(x, Wq, Wk, Wv, q, k, vt);

    dim3 gB(256), blkB(512);
    size_t ldsB = 145408;
    attn_kernel<<<gB, blkB, ldsB, stream>>>(q, k, vt, mask, out);
}

// Round 10
// 145.636 us; speedup vs baseline: 1.0272x; 1.0272x over previous
//
#include <hip/hip_runtime.h>

// Round 10: R8 skeleton + KVBLK=32 super-iteration (softmax/P/PV once per 32 keys),
// exp2-domain softmax (log2e folded into q scale). Shared staging, barrier+vmcnt(0)
// per 16-key subtile (R8 cadence). V: 2 slots/group staged at even subtiles.
//   d_in: 0=x f32, 1=mask i32, 2=Wk, 3=Wq, 4=Wv
// ws (f16): qT [BT/32][8192] | kT [BT/16][4096] | vT [BT/16][4096]
//   qT: [(qh*8+kc)*512 + l4*128 + tok*8 + j]  (x log2e/16 folded)
//   kT: [kc*512 + ch*128 + key*8 + j]   <-> K[16t+key][kc*32+ch*8+j]
//   vT: [dt*512 + kh*256 + d31*8 + j]   <-> V^T[dt*32+d31][16t+kh*8+j]

typedef __attribute__((ext_vector_type(8)))  _Float16 f16x8;
typedef __attribute__((ext_vector_type(4)))  _Float16 f16x4;
typedef __attribute__((ext_vector_type(4)))  float    f32x4;
typedef __attribute__((ext_vector_type(16))) float    f32x16;

constexpr int Bb = 4;
constexpr int Tt = 4096;
constexpr int Cc = 256;
constexpr int BT = Bb * Tt;
constexpr int NT = 64;                 // 16-key subtiles per warp (64 x 16 = 1024 keys)

#define MFMA16(a, b, c) __builtin_amdgcn_mfma_f32_16x16x32_f16((a), (b), (c), 0, 0, 0)
#define MFMA32(a, b, c) __builtin_amdgcn_mfma_f32_32x32x16_f16((a), (b), (c), 0, 0, 0)

__device__ __forceinline__ void gl16(const _Float16* gp, char* lp) {
    __builtin_amdgcn_global_load_lds(
        (const __attribute__((address_space(1))) void*)gp,
        (__attribute__((address_space(3))) void*)lp, 16, 0, 0);
}

// ---------------- Kernel A: fused QKV projection ----------------
__global__ __launch_bounds__(256) void qkv_proj(
    const float* __restrict__ x,
    const float* __restrict__ Wq, const float* __restrict__ Wk,
    const float* __restrict__ Wv,
    _Float16* __restrict__ qo, _Float16* __restrict__ ko,
    _Float16* __restrict__ vto)
{
    extern __shared__ _Float16 sm[];
    _Float16* xs = sm;              // [128][264]
    _Float16* wsm = sm + 128 * 264; // [128][264]

    const int tid = threadIdx.x;
    const int m0  = blockIdx.x * 128;
    const int ny  = blockIdx.y;
    const int mat = ny >> 1;              // 0=q 1=k 2=v
    const int d0  = (ny & 1) * 128;
    const float* W = (mat == 0) ? Wq : (mat == 1 ? Wk : Wv);

#pragma unroll
    for (int i = 0; i < 32; ++i) {
        int flat = i * 256 + tid;
        int r = flat >> 6, c4 = (flat & 63) << 2;
        float4 v = *reinterpret_cast<const float4*>(x + (size_t)(m0 + r) * Cc + c4);
        f16x4 h = { (_Float16)v.x, (_Float16)v.y, (_Float16)v.z, (_Float16)v.w };
        *reinterpret_cast<f16x4*>(xs + r * 264 + c4) = h;
    }
#pragma unroll
    for (int i = 0; i < 32; ++i) {
        int flat = i * 256 + tid;
        int r = flat >> 6, c4 = (flat & 63) << 2;
        float4 v = *reinterpret_cast<const float4*>(W + (size_t)(d0 + r) * Cc + c4);
        f16x4 h = { (_Float16)v.x, (_Float16)v.y, (_Float16)v.z, (_Float16)v.w };
        *reinterpret_cast<f16x4*>(wsm + r * 264 + c4) = h;
    }
    __syncthreads();

    const int w = tid >> 6, lane = tid & 63;
    const int lr = lane & 15, lg = lane >> 4;

    f32x4 acc[2][8] = {};

#pragma unroll
    for (int kc = 0; kc < 8; ++kc) {
        const int c0 = kc * 32 + lg * 8;
        f16x8 xf[2], wf[8];
#pragma unroll
        for (int mb = 0; mb < 2; ++mb)
            xf[mb] = *reinterpret_cast<const f16x8*>(xs + (w * 32 + mb * 16 + lr) * 264 + c0);
#pragma unroll
        for (int db = 0; db < 8; ++db)
            wf[db] = *reinterpret_cast<const f16x8*>(wsm + (db * 16 + lr) * 264 + c0);
        if (mat != 2) {
#pragma unroll
            for (int mb = 0; mb < 2; ++mb)
#pragma unroll
                for (int db = 0; db < 8; ++db)
                    acc[mb][db] = MFMA16(wf[db], xf[mb], acc[mb][db]);   // D[d][tok]
        } else {
#pragma unroll
            for (int mb = 0; mb < 2; ++mb)
#pragma unroll
                for (int db = 0; db < 8; ++db)
                    acc[mb][db] = MFMA16(xf[mb], wf[db], acc[mb][db]);   // D[tok][d]
        }
    }

    if (mat != 2) {
        // q scale: 1/sqrt(256) * log2(e)  (softmax runs in base-2 domain)
        const float sc = (mat == 0) ? 0.0625f * 1.44269504f : 1.0f;
        const int jj  = (lg & 1) * 4;
#pragma unroll
        for (int mb = 0; mb < 2; ++mb)
#pragma unroll
            for (int db = 0; db < 8; ++db) {
                int m  = m0 + w * 32 + mb * 16 + lr;
                int c  = d0 + db * 16 + lg * 4;
                int kc = c >> 5;
                int ch = (c >> 3) & 3;
                f32x4 a = acc[mb][db];
                f16x4 h = { (_Float16)(a.x * sc), (_Float16)(a.y * sc),
                            (_Float16)(a.z * sc), (_Float16)(a.w * sc) };
                if (mat == 0) {
                    size_t off = (size_t)(m >> 5) * 8192 + (((m >> 4) & 1) * 8 + kc) * 512
                               + ch * 128 + (m & 15) * 8 + jj;
                    *reinterpret_cast<f16x4*>(qo + off) = h;
                } else {
                    size_t off = (size_t)(m >> 4) * 4096 + kc * 512
                               + ch * 128 + (m & 15) * 8 + jj;
                    *reinterpret_cast<f16x4*>(ko + off) = h;
                }
            }
    } else {
        const int jj = (lg & 1) * 4;
        const int kh = (lg >> 1) & 1;
#pragma unroll
        for (int mb = 0; mb < 2; ++mb)
#pragma unroll
            for (int db = 0; db < 8; ++db) {
                int d = d0 + db * 16 + lr;
                int m = m0 + w * 32 + mb * 16 + lg * 4;
                f32x4 a = acc[mb][db];
                f16x4 h = { (_Float16)a.x, (_Float16)a.y, (_Float16)a.z, (_Float16)a.w };
                size_t off = (size_t)(m >> 4) * 4096 + (d >> 5) * 512
                           + kh * 256 + (d & 31) * 8 + jj;
                *reinterpret_cast<f16x4*>(vto + off) = h;
            }
    }
}

// ---------------- Kernel B: flash attention ----------------
// LDS map (bytes): [0,65536)      K: 4 g x 2 dbuf x 8 KB
//                  [65536,131072) V: 4 g x 2 slot x 8 KB
//                  [131072,151552) per-warp P [8][32][40] f16
//                  [151552,152576) mex f32[2][4][32]; [152576,153600) lex
// epilogue reuses [0,132096) as oex f32[4][32][258]
__global__ __launch_bounds__(512, 2) void attn_kernel(
    const _Float16* __restrict__ qb, const _Float16* __restrict__ kb,
    const _Float16* __restrict__ vtb, const int* __restrict__ mask,
    float* __restrict__ outp)
{
    extern __shared__ char smraw[];
    float* mex32 = (float*)(smraw + 151552);
    float* lex32 = (float*)(smraw + 152576);
    float* oexf  = (float*)smraw;

    const int tid = threadIdx.x, w = tid >> 6, lane = tid & 63;
    const int qw = w >> 2, g = w & 3;
    const int l15 = lane & 15, l4 = lane >> 4;
    const int l31 = lane & 31, l5 = lane >> 5;

    const int bid = blockIdx.x;
    const int b   = (bid & 7) >> 1;                    // batch -> XCD pair
    const int qt  = ((bid >> 3) << 1) | (bid & 1);     // [0,64)
    const int q0  = qt * 64;
    const size_t base = (size_t)b * Tt * Cc;
    const int* maskb = mask + (size_t)b * Tt;
    const _Float16* kTb = kb + base;
    const _Float16* vTb = vtb + base;

    // Q fragments: Q[q0 + qw*32 + qh*16 + l15][kc*32 + l4*8 + j]
    f16x8 qf[2][8];
    {
        const _Float16* qTb = qb + (size_t)(b * 128 + qt * 2 + qw) * 8192;
#pragma unroll
        for (int qh = 0; qh < 2; ++qh)
#pragma unroll
            for (int kc = 0; kc < 8; ++kc)
                qf[qh][kc] = *reinterpret_cast<const f16x8*>(
                    qTb + (qh * 8 + kc) * 512 + l4 * 128 + l15 * 8);
    }

    char* kreg = smraw + g * 16384;               // K: 2 x 8 KB dbuf
    char* vreg = smraw + 65536 + g * 16384;       // V: 2 x 8 KB slots
    _Float16* pw = (_Float16*)(smraw + 131072) + w * 1280;   // [32][40]

    f32x16 o[8] = {};                  // O^T[d = dt*32+(r&3)+8*(r>>2)+4*l5][q=l31]
    float m0r = -60.f, m1r = -60.f, l0r = 0.f, l1r = 0.f;

    // staging roles: qw0 stages K, qw1 stages V (linear 8 KB copies)
    auto STAGE_K = [&](int t) {        // K(t) -> dbuf slot t&1
        char* dst = kreg + (t & 1) * 8192;
        const _Float16* src = kTb + (size_t)(t * 4 + g) * 4096 + lane * 8;
#pragma unroll
        for (int j = 0; j < 8; ++j) gl16(src + j * 512, dst + j * 1024);
    };
    auto STAGE_V = [&](int t) {        // V(t) -> slot t&1
        char* dst = vreg + (t & 1) * 8192;
        const _Float16* src = vTb + (size_t)(t * 4 + g) * 4096 + lane * 8;
#pragma unroll
        for (int j = 0; j < 8; ++j) gl16(src + j * 512, dst + j * 1024);
    };

    if (qw == 0) STAGE_K(0);
    asm volatile("s_waitcnt vmcnt(0)" ::: "memory");

    f32x4 s00, s01, s10, s11;          // S^T[a][qh]: key = a*16 + l4*4 + r, q = qh*16+l15

#pragma unroll 1
    for (int t = 0; t < NT; ++t) {
        __syncthreads();               // subtile t: K(t) ready in dbuf[t&1]
        // staging for the future (lands by this subtile's vmcnt(0))
        if (qw == 0) { if (t + 1 < NT) STAGE_K(t + 1); }
        else if (!(t & 1)) { STAGE_V(t); if (t + 1 < NT) STAGE_V(t + 1); }

        const _Float16* kb_ = (const _Float16*)(kreg + (t & 1) * 8192);
        int4 mc = *reinterpret_cast<const int4*>(maskb + (t * 4 + g) * 16 + l4 * 4);

        // QK: S^T[key = l4*4 + r][q = qh*16 + l15]
        f32x4 sa = { 0.f, 0.f, 0.f, 0.f }, sb = { 0.f, 0.f, 0.f, 0.f };
        __builtin_amdgcn_s_setprio(1);
#pragma unroll
        for (int kc = 0; kc < 8; ++kc) {
            f16x8 kf = *reinterpret_cast<const f16x8*>(kb_ + kc * 512 + l4 * 128 + l15 * 8);
            sa = MFMA16(kf, qf[0][kc], sa);
            sb = MFMA16(kf, qf[1][kc], sb);
        }
        __builtin_amdgcn_s_setprio(0);

        if (mc.x == 0) { sa[0] = -1e30f; sb[0] = -1e30f; }
        if (mc.y == 0) { sa[1] = -1e30f; sb[1] = -1e30f; }
        if (mc.z == 0) { sa[2] = -1e30f; sb[2] = -1e30f; }
        if (mc.w == 0) { sa[3] = -1e30f; sb[3] = -1e30f; }

        if (!(t & 1)) {
            s00 = sa; s01 = sb;        // first half of the 32-key super-tile
        } else {
            s10 = sa; s11 = sb;

            // ---- softmax over 32 keys (base-2 domain), once per super-tile ----
            float t0 = fmaxf(fmaxf(fmaxf(s00[0], s00[1]), fmaxf(s00[2], s00[3])),
                             fmaxf(fmaxf(s10[0], s10[1]), fmaxf(s10[2], s10[3])));
            float t1 = fmaxf(fmaxf(fmaxf(s01[0], s01[1]), fmaxf(s01[2], s01[3])),
                             fmaxf(fmaxf(s11[0], s11[1]), fmaxf(s11[2], s11[3])));
            t0 = fmaxf(t0, __shfl_xor(t0, 16, 64)); t0 = fmaxf(t0, __shfl_xor(t0, 32, 64));
            t1 = fmaxf(t1, __shfl_xor(t1, 16, 64)); t1 = fmaxf(t1, __shfl_xor(t1, 32, 64));

            if (__any(t0 > m0r + 11.54f || t1 > m1r + 11.54f)) {   // defer-max (2^11.54≈e^8)
                float mn0 = fmaxf(m0r, t0), mn1 = fmaxf(m1r, t1);
                float c0 = exp2f(m0r - mn0), c1 = exp2f(m1r - mn1);
                m0r = mn0; m1r = mn1; l0r *= c0; l1r *= c1;
                float cs = (lane & 16) ? c1 : c0;                  // o cols: q = l31
#pragma unroll
                for (int dt = 0; dt < 8; ++dt) o[dt] *= cs;
            }

            float rs0 = 0.f, rs1 = 0.f;
#pragma unroll
            for (int r = 0; r < 4; ++r) {
                float p;
                p = exp2f(s00[r] - m0r); s00[r] = p; rs0 += p;
                p = exp2f(s10[r] - m0r); s10[r] = p; rs0 += p;
                p = exp2f(s01[r] - m1r); s01[r] = p; rs1 += p;
                p = exp2f(s11[r] - m1r); s11[r] = p; rs1 += p;
            }
            rs0 += __shfl_xor(rs0, 16, 64); rs0 += __shfl_xor(rs0, 32, 64);
            rs1 += __shfl_xor(rs1, 16, 64); rs1 += __shfl_xor(rs1, 32, 64);
            l0r += rs0; l1r += rs1;

            // P -> pw[q][key] f16 (32 keys); reread as PV B-frags
            {
                f16x4 h;
                h = (f16x4){ (_Float16)s00[0], (_Float16)s00[1], (_Float16)s00[2], (_Float16)s00[3] };
                *reinterpret_cast<f16x4*>(pw + l15 * 40 + l4 * 4) = h;
                h = (f16x4){ (_Float16)s10[0], (_Float16)s10[1], (_Float16)s10[2], (_Float16)s10[3] };
                *reinterpret_cast<f16x4*>(pw + l15 * 40 + 16 + l4 * 4) = h;
                h = (f16x4){ (_Float16)s01[0], (_Float16)s01[1], (_Float16)s01[2], (_Float16)s01[3] };
                *reinterpret_cast<f16x4*>(pw + (16 + l15) * 40 + l4 * 4) = h;
                h = (f16x4){ (_Float16)s11[0], (_Float16)s11[1], (_Float16)s11[2], (_Float16)s11[3] };
                *reinterpret_cast<f16x4*>(pw + (16 + l15) * 40 + 16 + l4 * 4) = h;
            }
            f16x8 pf0 = *reinterpret_cast<const f16x8*>(pw + l31 * 40 + l5 * 8);
            f16x8 pf1 = *reinterpret_cast<const f16x8*>(pw + l31 * 40 + 16 + l5 * 8);

            // PV: O^T += V^T P^T over both 16-key slots
            __builtin_amdgcn_s_setprio(1);
#pragma unroll
            for (int dt = 0; dt < 8; ++dt) {
                f16x8 vf0 = *reinterpret_cast<const f16x8*>(
                    vreg + 0 * 8192 + dt * 1024 + l5 * 512 + l31 * 16);
                o[dt] = MFMA32(vf0, pf0, o[dt]);
                f16x8 vf1 = *reinterpret_cast<const f16x8*>(
                    vreg + 1 * 8192 + dt * 1024 + l5 * 512 + l31 * 16);
                o[dt] = MFMA32(vf1, pf1, o[dt]);
            }
            __builtin_amdgcn_s_setprio(0);
        }

        asm volatile("s_waitcnt vmcnt(0)" ::: "memory");   // my stage DMAs landed
    }
    __syncthreads();   // all warps done with K/V LDS; safe to reuse as oex

    // ---- epilogue: 4-group split-K merge, two qw passes (base-2) ----
    if (l4 == 0) {
        mex32[(qw * 4 + g) * 32 + l15]      = m0r;
        mex32[(qw * 4 + g) * 32 + 16 + l15] = m1r;
        lex32[(qw * 4 + g) * 32 + l15]      = l0r;
        lex32[(qw * 4 + g) * 32 + 16 + l15] = l1r;
    }
    __syncthreads();

    float mq = (lane & 16) ? m1r : m0r;
    float mst = -1e30f;
#pragma unroll
    for (int g2 = 0; g2 < 4; ++g2)
        mst = fmaxf(mst, mex32[(qw * 4 + g2) * 32 + l31]);
    float osc = exp2f(mq - mst);

#pragma unroll 1
    for (int s = 0; s < 2; ++s) {
        if (qw == s) {
            float* og = oexf + g * (32 * 258);
#pragma unroll
            for (int dt = 0; dt < 8; ++dt)
#pragma unroll
                for (int r = 0; r < 16; ++r) {
                    int d = dt * 32 + (r & 3) + 8 * (r >> 2) + 4 * l5;
                    og[l31 * 258 + d] = o[dt][r] * osc;
                }
        }
        __syncthreads();
        {
            const int q = tid >> 4, dg = tid & 15;
            float mA = mex32[(s * 4 + 0) * 32 + q], mB = mex32[(s * 4 + 1) * 32 + q];
            float mC = mex32[(s * 4 + 2) * 32 + q], mD = mex32[(s * 4 + 3) * 32 + q];
            float ms = fmaxf(fmaxf(mA, mB), fmaxf(mC, mD));
            float lt = lex32[(s * 4 + 0) * 32 + q] * exp2f(mA - ms)
                     + lex32[(s * 4 + 1) * 32 + q] * exp2f(mB - ms)
                     + lex32[(s * 4 + 2) * 32 + q] * exp2f(mC - ms)
                     + lex32[(s * 4 + 3) * 32 + q] * exp2f(mD - ms);
            float inv = 1.f / lt;
#pragma unroll
            for (int i = 0; i < 4; ++i) {
                int d0 = dg * 16 + i * 4;
                f32x4 a = *reinterpret_cast<const f32x4*>(oexf + q * 258 + d0);
#pragma unroll
                for (int g2 = 1; g2 < 4; ++g2) {
                    f32x4 tt = *reinterpret_cast<const f32x4*>(
                        oexf + g2 * (32 * 258) + q * 258 + d0);
                    a[0] += tt[0]; a[1] += tt[1]; a[2] += tt[2]; a[3] += tt[3];
                }
                a[0] *= inv; a[1] *= inv; a[2] *= inv; a[3] *= inv;
                *reinterpret_cast<f32x4*>(
                    outp + base + (size_t)(q0 + s * 32 + q) * Cc + d0) = a;
            }
        }
        __syncthreads();
    }
}

extern "C" void kernel_launch(void* const* d_in, const int* in_sizes, int n_in,
                              void* d_out, int out_size, void* d_ws, size_t ws_size,
                              hipStream_t stream)
{
    (void)in_sizes; (void)n_in; (void)out_size; (void)ws_size;
    const float* x   = (const float*)d_in[0];
    const int*  mask = (const int*)d_in[1];
    const float* Wk  = (const float*)d_in[2];
    const float* Wq  = (const float*)d_in[3];
    const float* Wv  = (const float*)d_in[4];
    float* out = (float*)d_out;

    _Float16* q  = (_Float16*)d_ws;
    _Float16* k  = q + (size_t)BT * Cc;
    _Float16* vt = k + (size_t)BT * Cc;

    dim3 gA(128, 6), blkA(256);
    size_t ldsA = (size_t)(128 + 128) * 264 * sizeof(_Float16);
    qkv_proj<<<gA, blkA, ldsA, stream>>>(x, Wq, Wk, Wv, q, k, vt);

    dim3 gB(256), blkB(512);
    size_t ldsB = 153600;
    attn_kernel<<<gB, blkB, ldsB, stream>>>(q, k, vt, mask, out);
}